// Round 16
// baseline (249.185 us; speedup 1.0000x reference)
//
#include <hip/hip_runtime.h>
#include <hip/hip_bf16.h>
#include <math.h>

#define BATCH 16
#define ICH 64
#define OCH 64
#define HH 256
#define WW 256
#define HW 65536
#define EPS 1e-5f
#define C_EQ (1.0f / 24.0f)

typedef __attribute__((ext_vector_type(8))) short short8;     // bf16x8 MFMA operand
typedef __attribute__((ext_vector_type(4))) float floatx4;    // fp32x4 accumulator (16x16)
typedef __attribute__((ext_vector_type(16))) float floatx16;  // fp32x16 accumulator (32x32)

// d_ws: [0,73728) A-frags 16x16 ; [73728,147456) A-frags 32x32 ; then padded xT
#define AFRAG_BYTES 73728
#define A2_OFF 73728
#define XT_OFF 147456
#define XT_PIX 258
#define XT_ROWB (XT_PIX * 128)                          // 33024
#define XT_IMGB ((size_t)XT_PIX * XT_PIX * 128)        // 8520192
#define WS_NEEDED ((size_t)XT_OFF + (size_t)BATCH * XT_IMGB)

#define AS1 __attribute__((address_space(1)))
#define AS3 __attribute__((address_space(3)))

static __device__ __forceinline__ unsigned short f2bf(float v) {
    __hip_bfloat16 b = __float2bfloat16(v);
    return *reinterpret_cast<unsigned short*>(&b);
}
static __device__ __forceinline__ unsigned int pk2(float a, float b) {
    return (unsigned int)f2bf(a) | ((unsigned int)f2bf(b) << 16);
}

// ============ kernel 1: demodulate weights -> BOTH A-frag layouts ============
__global__ void weight_prep_kernel(const float* __restrict__ wgt,
                                   unsigned int* __restrict__ wsout)
{
    const int tid = threadIdx.x;
    const int oc  = blockIdx.x * 16 + (tid >> 2);
    const int q   = tid & 3;
    const float* wb = wgt + ((size_t)oc * 64 + q * 16) * 9;

    float s = 0.f;
    #pragma unroll 4
    for (int i = 0; i < 36; ++i) {
        const float4 v = reinterpret_cast<const float4*>(wb)[i];
        s += v.x*v.x + v.y*v.y + v.z*v.z + v.w*v.w;
    }
    s += __shfl_xor(s, 1, 64);
    s += __shfl_xor(s, 2, 64);
    const float sc = C_EQ * rsqrtf(s * (C_EQ * C_EQ) + EPS);

    // --- 16x16 table (validated R4-R15, unchanged) ---
    const int h = q >> 1;
    #pragma unroll
    for (int s2 = 0; s2 < 2; ++s2) {
        const int G = (q & 1) * 2 + s2;
        #pragma unroll
        for (int jp = 0; jp < 4; ++jp) {
            const float* r0 = wb + (8 * s2 + 2 * jp) * 9;
            const float* r1 = r0 + 9;
            #pragma unroll
            for (int t = 0; t < 9; ++t) {
                const unsigned int d = (unsigned)f2bf(r0[t] * sc)
                                     | ((unsigned)f2bf(r1[t] * sc) << 16);
                wsout[(((h * 9 + t) * 64 + oc) * 4 + G) * 4 + jp] = d;
            }
        }
    }
    // --- 32x32 table: chunk (q,t); 16B entry at ((q*9+t)*2 + oc>>5)*64 + (oc&31) + 32g ---
    // lane (oc&31)+32g holds bf16[8] = w[oc][16q + 8g + j][t]*sc, j ascending.
    unsigned int* w2 = wsout + (A2_OFF / 4);
    #pragma unroll
    for (int g = 0; g < 2; ++g) {
        #pragma unroll
        for (int t = 0; t < 9; ++t) {
            const int idx16 = ((q * 9 + t) * 2 + (oc >> 5)) * 64 + ((oc & 31) + (g << 5));
            #pragma unroll
            for (int jp = 0; jp < 4; ++jp)
                w2[idx16 * 4 + jp] = pk2(wb[(8*g + 2*jp) * 9 + t] * sc,
                                         wb[(8*g + 2*jp + 1) * 9 + t] * sc);
        }
    }
}

// ============ kernel 2: NCHW fp32 -> zero-padded [b][h+1][w+1][ic] bf16 (validated R6-R15) ============
__global__ __launch_bounds__(256, 8) void transpose_pad_kernel(
    const float* __restrict__ x, char* __restrict__ xT)
{
    const int tid  = threadIdx.x;
    const int lane = tid & 63;
    const int wvv  = tid >> 6;
    const int cb = blockIdx.x, hh = blockIdx.y, b = blockIdx.z;
    char* rowbase = xT + (size_t)b * XT_IMGB + (size_t)hh * XT_ROWB;
    const uint4 z4 = make_uint4(0u, 0u, 0u, 0u);

    if (hh == 0 || hh == XT_PIX - 1) {
        char* base = rowbase + (size_t)(cb * 64 + 1) * 128;
        *reinterpret_cast<uint4*>(base + tid * 32)      = z4;
        *reinterpret_cast<uint4*>(base + tid * 32 + 16) = z4;
        if (cb == 0 && tid < 8)
            *reinterpret_cast<uint4*>(rowbase + tid * 16) = z4;
        if (cb == 3 && tid >= 8 && tid < 16)
            *reinterpret_cast<uint4*>(rowbase + (size_t)257 * 128 + (tid - 8) * 16) = z4;
        return;
    }
    if (cb == 0 && tid < 8)
        *reinterpret_cast<uint4*>(rowbase + tid * 16) = z4;
    if (cb == 3 && tid >= 8 && tid < 16)
        *reinterpret_cast<uint4*>(rowbase + (size_t)257 * 128 + (tid - 8) * 16) = z4;

    __shared__ float lds[64 * 65];
    const int h = hh - 1;
    const float* xrow = x + (size_t)b * ICH * HW + (size_t)h * WW + cb * 64;
    float v[16];
    #pragma unroll
    for (int i = 0; i < 16; ++i)
        v[i] = xrow[(size_t)(i * 4 + wvv) * HW + lane];
    #pragma unroll
    for (int i = 0; i < 16; ++i)
        lds[lane * 65 + i * 4 + wvv] = v[i];
    __syncthreads();

    const int col = tid >> 2;
    const int g   = tid & 3;
    const float* lp = &lds[col * 65];
    char* dst = rowbase + (size_t)(cb * 64 + col + 1) * 128;
    #pragma unroll
    for (int r = 0; r < 2; ++r) {
        const int ich = r * 32 + g * 8;
        uint4 dw;
        dw.x = pk2(lp[ich + 0], lp[ich + 1]);
        dw.y = pk2(lp[ich + 2], lp[ich + 3]);
        dw.z = pk2(lp[ich + 4], lp[ich + 5]);
        dw.w = pk2(lp[ich + 6], lp[ich + 7]);
        *reinterpret_cast<uint4*>(dst + r * 64 + g * 16) = dw;
    }
}

// ============ kernel 3: og-split conv on 32x32x16 MFMA (halved LDS B-traffic) ============
// block: 4 waves; tile 4 rows x 64 cols x 64 oc. Wave wv: oc-half (wv&1)*32, col-half (wv>>1)*32.
// 12 phases (q=ic-quarter, kw): 6 ds_read_b128 + 12 MFMA(32x32x16). A[9] trio-reload (R15 cadence).
__global__ __launch_bounds__(256, 3) void conv_mfma_32(
    const char* __restrict__ ws, float* __restrict__ out)
{
    __shared__ __align__(16) char lx[6 * 8448];   // 50688 B, content identical to R15

    const int tid  = threadIdx.x;
    const int lane = tid & 63;
    const int wv   = tid >> 6;
    const int och  = wv & 1;    // oc half
    const int ch   = wv >> 1;   // col half
    const int gl   = lane >> 5; // k-group within MFMA

    // XCD-aware swizzle, ry-fastest (validated R15)
    const int bid = blockIdx.x;
    const int wg  = (bid & 7) * 512 + (bid >> 3);
    const int b   = wg >> 8;
    const int cbk = (wg >> 6) & 3;
    const int ry  = wg & 63;
    const int gc0 = cbk * 64;
    const int gr0 = ry * 4;

    const char* xTb = ws + XT_OFF + (size_t)b * XT_IMGB;

    // ---- async stage (validated R8-R15, byte-identical LDS content) ----
    const unsigned laneoff = ((unsigned)(lane >> 3) << 7)
                           + ((unsigned)((lane & 7) ^ (lane >> 3)) << 4);
    #pragma unroll
    for (int t = 0; t < 14; ++t) {
        const int i = wv + 4 * t;
        if (i >= 54) break;                       // wave-uniform
        const int row = i / 9;
        const int k   = i - row * 9;
        const char* src = xTb + (size_t)(gr0 + row) * XT_ROWB
                        + ((unsigned)gc0 << 7) + ((unsigned)k << 10) + laneoff;
        if (k < 8 || lane < 16)
            __builtin_amdgcn_global_load_lds(
                (const AS1 void*)src,
                (AS3 void*)&lx[row * 8448 + (k << 10)], 16, 0, 0);
    }

    // ---- A-frags (32x32 table): 9 resident taps for current quarter, trio-reloaded ----
    const unsigned abase2 = (unsigned)((och << 10) + (lane << 4));
    short8 A[9];
#define LOADA2(j, q) A[j] = *reinterpret_cast<const short8*>( \
    ws + A2_OFF + (((q) * 9 + (j)) << 11) + abase2)
    #pragma unroll
    for (int j = 0; j < 9; ++j) LOADA2(j, 0);

    // per-lane B col parts: px = ch*32 + (lane&31) + kw
    int pxb[3], px7[3];
    #pragma unroll
    for (int kw = 0; kw < 3; ++kw) {
        const int px = (ch << 5) + (lane & 31) + kw;
        pxb[kw] = px << 7;
        px7[kw] = px & 7;
    }

    floatx16 acc[4];
    #pragma unroll
    for (int fr = 0; fr < 4; ++fr)
        #pragma unroll
        for (int r = 0; r < 16; ++r) acc[fr][r] = 0.f;

    __syncthreads();   // drains stage + A loads

    // ---- main loop: 12 phases. Phase p: q=p/3, kw=p%3. Reload trio (p-1)%3 <- quarter p/3(+1).
    #pragma unroll
    for (int p = 0; p < 12; ++p) {
        const int q = p / 3, kw = p % 3;
        if (p >= 1 && p <= 9) {
            const int kwp = (p - 1) % 3, qp = (p - 1) / 3 + 1;
            LOADA2(kwp,     qp);
            LOADA2(kwp + 3, qp);
            LOADA2(kwp + 6, qp);
        }
        // 6 B-frags: input rows 0..5, ic-slot (2q+gl)^(px&7)
        uint4 B[6];
        const int so = ((q << 1) | gl);
        #pragma unroll
        for (int j = 0; j < 6; ++j)
            B[j] = *reinterpret_cast<const uint4*>(
                &lx[j * 8448 + pxb[kw] + ((so ^ px7[kw]) << 4)]);
        #pragma unroll
        for (int kh = 0; kh < 3; ++kh) {
            const short8 a = A[kh * 3 + kw];
            #pragma unroll
            for (int fr = 0; fr < 4; ++fr)
                acc[fr] = __builtin_amdgcn_mfma_f32_32x32x16_bf16(
                    a, __builtin_bit_cast(short8, B[fr + kh]), acc[fr], 0, 0, 0);
        }
    }
#undef LOADA2

    // ---- epilogue: block-cooperative in-LDS transpose; READ SIDE VERBATIM (R12/R14/R15).
    // Write side: D layout (m74/m101): oc_local32 = (r&3)+8*(r>>2)+4*gl, col = ch*32+(lane&31).
    float* lf = (float*)lx;
    #pragma unroll
    for (int half = 0; half < 2; ++half) {
        __syncthreads();   // previous readers done
        if (och == half) {
            const int col = (ch << 5) + (lane & 31);
            #pragma unroll
            for (int fr = 0; fr < 4; ++fr)
                #pragma unroll
                for (int r = 0; r < 16; ++r) {
                    const int ocl = (r & 3) + ((r >> 2) << 3) + (gl << 2);
                    lf[(ocl * 4 + fr) * 68 + col] = acc[fr][r];
                }
        }
        __syncthreads();
        const int qq = tid & 15;
        #pragma unroll
        for (int j = 0; j < 8; ++j) {
            const int row = (tid >> 4) + (j << 4);       // 0..127
            const int ocl = row >> 2, fr = row & 3;
            const float4 v = *reinterpret_cast<const float4*>(&lf[row * 68 + (qq << 2)]);
            float* op = out + ((size_t)b * OCH + half * 32 + ocl) * HW
                            + (size_t)(gr0 + fr) * WW + gc0 + (qq << 2);
            *reinterpret_cast<float4*>(op) = v;          // 256B contiguous runs
        }
    }
}

// ============ fallback: R4 validated LDS-staging conv (if ws too small) ============
#define TR 4
#define TC 64
#define XROWS 6
#define XCOLS 66
#define XPIXB 64
#define XROWB (XCOLS * XPIXB)
#define XHALFB (XROWS * XROWB)
#define LDS_BYTES (2 * XHALFB)

__global__ __launch_bounds__(256, 2) void conv_mfma_fallback(
    const float* __restrict__ x,
    const unsigned int* __restrict__ wfrag,
    float* __restrict__ out)
{
    __shared__ __align__(16) char lds[LDS_BYTES];
    const int tid  = threadIdx.x;
    const int lane = tid & 63;
    const int wv   = tid >> 6;
    const int n_l  = lane & 15;
    const int G_l  = lane >> 4;

    short8 afrag[18];
    {
        const int oc_l = (wv << 4) + n_l;
        const char* wsb = (const char*)wfrag;
        #pragma unroll
        for (int kc = 0; kc < 18; ++kc)
            afrag[kc] = *reinterpret_cast<const short8*>(
                wsb + (((kc * 64 + oc_l) * 4 + G_l) << 4));
    }

    const int gr0 = blockIdx.y * TR;
    const int gc0 = blockIdx.x * TC;
    const int b   = blockIdx.z;
    const float* xb = x + (size_t)b * ICH * HW;

    for (int p = wv; p < 48; p += 4) {
        const int h  = p / 24;
        const int pr = (p % 24) >> 2;
        const int G  = p & 3;
        const int gr = gr0 - 1 + pr;
        const int icb = h * 32 + G * 8;
        const bool rok = ((unsigned)gr < (unsigned)HH);
        {
            const float* src = xb + (size_t)icb * HW + (size_t)gr * WW + gc0 + lane;
            float v[8];
            #pragma unroll
            for (int qq = 0; qq < 8; ++qq) v[qq] = rok ? src[(size_t)qq * HW] : 0.f;
            const int pc = lane + 1;
            const int addr = h*XHALFB + pr*XROWB + pc*XPIXB + ((G ^ ((pc >> 1) & 3)) << 4);
            uint4 w4; w4.x = pk2(v[0], v[1]); w4.y = pk2(v[2], v[3]);
            w4.z = pk2(v[4], v[5]); w4.w = pk2(v[6], v[7]);
            *reinterpret_cast<uint4*>(&lds[addr]) = w4;
        }
        if (lane < 2) {
            const int pc = lane * 65;
            const int gc = gc0 - 1 + pc;
            const bool ok = rok && ((unsigned)gc < (unsigned)WW);
            const float* src = xb + (size_t)icb * HW + (size_t)gr * WW + gc;
            float v[8];
            #pragma unroll
            for (int qq = 0; qq < 8; ++qq) v[qq] = ok ? src[(size_t)qq * HW] : 0.f;
            const int addr = h*XHALFB + pr*XROWB + pc*XPIXB + ((G ^ ((pc >> 1) & 3)) << 4);
            uint4 w4; w4.x = pk2(v[0], v[1]); w4.y = pk2(v[2], v[3]);
            w4.z = pk2(v[4], v[5]); w4.w = pk2(v[6], v[7]);
            *reinterpret_cast<uint4*>(&lds[addr]) = w4;
        }
    }
    __syncthreads();

    int colp[4][3];
    #pragma unroll
    for (int cbq = 0; cbq < 4; ++cbq)
        #pragma unroll
        for (int kw = 0; kw < 3; ++kw) {
            const int pcv = cbq * 16 + n_l + kw;
            colp[cbq][kw] = pcv * XPIXB + ((G_l ^ ((pcv >> 1) & 3)) << 4);
        }

    floatx4 acc[16];
    #pragma unroll
    for (int f = 0; f < 16; ++f) acc[f] = (floatx4){0.f, 0.f, 0.f, 0.f};

    #pragma unroll
    for (int kc = 0; kc < 18; ++kc) {
        const int h = kc / 9, tap = kc % 9;
        const int kh = tap / 3, kw = tap % 3;
        #pragma unroll
        for (int f = 0; f < 16; ++f) {
            const int fr = f >> 2, cbq = f & 3;
            const short8 bfrag = *reinterpret_cast<const short8*>(
                &lds[h*XHALFB + (fr + kh)*XROWB + colp[cbq][kw]]);
            acc[f] = __builtin_amdgcn_mfma_f32_16x16x32_bf16(afrag[kc], bfrag, acc[f], 0, 0, 0);
        }
    }

    float* ob = out + ((size_t)(b*OCH + (wv << 4) + (G_l << 2)) * HW)
                    + (size_t)gr0 * WW + gc0 + n_l;
    #pragma unroll
    for (int f = 0; f < 16; ++f) {
        const int fr = f >> 2, cbq = f & 3;
        #pragma unroll
        for (int ri = 0; ri < 4; ++ri)
            ob[(size_t)ri * HW + fr * WW + cbq * 16] = acc[f][ri];
    }
}

extern "C" void kernel_launch(void* const* d_in, const int* in_sizes, int n_in,
                              void* d_out, int out_size, void* d_ws, size_t ws_size,
                              hipStream_t stream) {
    const float* x = (const float*)d_in[0];
    const float* w = (const float*)d_in[1];
    float* out = (float*)d_out;
    unsigned int* wsf = (unsigned int*)d_ws;

    weight_prep_kernel<<<dim3(4), 64, 0, stream>>>(w, wsf);

    if (ws_size >= WS_NEEDED) {
        char* xT = (char*)d_ws + XT_OFF;
        transpose_pad_kernel<<<dim3(4, XT_PIX, BATCH), 256, 0, stream>>>(x, xT);
        conv_mfma_32<<<dim3(4096), 256, 0, stream>>>((const char*)d_ws, out);
    } else {
        conv_mfma_fallback<<<dim3(4, 64, BATCH), 256, 0, stream>>>(x, wsf, out);
    }
}

// Round 17
// 207.293 us; speedup vs baseline: 1.2021x; 1.2021x over previous
//
#include <hip/hip_runtime.h>
#include <hip/hip_bf16.h>
#include <math.h>

#define BATCH 16
#define ICH 64
#define OCH 64
#define HH 256
#define WW 256
#define HW 65536
#define EPS 1e-5f
#define C_EQ (1.0f / 24.0f)

typedef __attribute__((ext_vector_type(8))) short short8;   // bf16x8 MFMA operand
typedef __attribute__((ext_vector_type(4))) float floatx4;  // fp32x4 accumulator

// d_ws layout: [0, 73728) bf16 A-frags ; then padded xT = [b][258][258] pixels of 128B
#define AFRAG_BYTES 73728
#define XT_PIX 258
#define XT_ROWB (XT_PIX * 128)                          // 33024
#define XT_IMGB ((size_t)XT_PIX * XT_PIX * 128)        // 8520192
#define WS_NEEDED (AFRAG_BYTES + (size_t)BATCH * XT_IMGB)   // 136396800

#define AS1 __attribute__((address_space(1)))
#define AS3 __attribute__((address_space(3)))

static __device__ __forceinline__ unsigned short f2bf(float v) {
    __hip_bfloat16 b = __float2bfloat16(v);
    return *reinterpret_cast<unsigned short*>(&b);
}
static __device__ __forceinline__ unsigned int pk2(float a, float b) {
    return (unsigned int)f2bf(a) | ((unsigned int)f2bf(b) << 16);
}

// ============ kernel 1: demodulate weights -> bf16 A-frag layout (validated R4-R15) ============
__global__ void weight_prep_kernel(const float* __restrict__ wgt,
                                   unsigned int* __restrict__ wsout)
{
    const int tid = threadIdx.x;
    const int oc  = blockIdx.x * 16 + (tid >> 2);
    const int q   = tid & 3;
    const float* wb = wgt + ((size_t)oc * 64 + q * 16) * 9;

    float s = 0.f;
    #pragma unroll 4
    for (int i = 0; i < 36; ++i) {
        const float4 v = reinterpret_cast<const float4*>(wb)[i];
        s += v.x*v.x + v.y*v.y + v.z*v.z + v.w*v.w;
    }
    s += __shfl_xor(s, 1, 64);
    s += __shfl_xor(s, 2, 64);
    const float sc = C_EQ * rsqrtf(s * (C_EQ * C_EQ) + EPS);

    const int h = q >> 1;
    #pragma unroll
    for (int s2 = 0; s2 < 2; ++s2) {
        const int G = (q & 1) * 2 + s2;
        #pragma unroll
        for (int jp = 0; jp < 4; ++jp) {
            const float* r0 = wb + (8 * s2 + 2 * jp) * 9;
            const float* r1 = r0 + 9;
            #pragma unroll
            for (int t = 0; t < 9; ++t) {
                const unsigned int d = (unsigned)f2bf(r0[t] * sc)
                                     | ((unsigned)f2bf(r1[t] * sc) << 16);
                wsout[(((h * 9 + t) * 64 + oc) * 4 + G) * 4 + jp] = d;
            }
        }
    }
}

// ============ kernel 2: NCHW fp32 -> zero-padded [b][h+1][w+1][ic] bf16 (validated R6-R15) ============
__global__ __launch_bounds__(256, 8) void transpose_pad_kernel(
    const float* __restrict__ x, char* __restrict__ xT)
{
    const int tid  = threadIdx.x;
    const int lane = tid & 63;
    const int wvv  = tid >> 6;
    const int cb = blockIdx.x, hh = blockIdx.y, b = blockIdx.z;
    char* rowbase = xT + (size_t)b * XT_IMGB + (size_t)hh * XT_ROWB;
    const uint4 z4 = make_uint4(0u, 0u, 0u, 0u);

    if (hh == 0 || hh == XT_PIX - 1) {
        char* base = rowbase + (size_t)(cb * 64 + 1) * 128;
        *reinterpret_cast<uint4*>(base + tid * 32)      = z4;
        *reinterpret_cast<uint4*>(base + tid * 32 + 16) = z4;
        if (cb == 0 && tid < 8)
            *reinterpret_cast<uint4*>(rowbase + tid * 16) = z4;
        if (cb == 3 && tid >= 8 && tid < 16)
            *reinterpret_cast<uint4*>(rowbase + (size_t)257 * 128 + (tid - 8) * 16) = z4;
        return;
    }
    if (cb == 0 && tid < 8)
        *reinterpret_cast<uint4*>(rowbase + tid * 16) = z4;
    if (cb == 3 && tid >= 8 && tid < 16)
        *reinterpret_cast<uint4*>(rowbase + (size_t)257 * 128 + (tid - 8) * 16) = z4;

    __shared__ float lds[64 * 65];
    const int h = hh - 1;
    const float* xrow = x + (size_t)b * ICH * HW + (size_t)h * WW + cb * 64;
    float v[16];
    #pragma unroll
    for (int i = 0; i < 16; ++i)
        v[i] = xrow[(size_t)(i * 4 + wvv) * HW + lane];
    #pragma unroll
    for (int i = 0; i < 16; ++i)
        lds[lane * 65 + i * 4 + wvv] = v[i];
    __syncthreads();

    const int col = tid >> 2;
    const int g   = tid & 3;
    const float* lp = &lds[col * 65];
    char* dst = rowbase + (size_t)(cb * 64 + col + 1) * 128;
    #pragma unroll
    for (int r = 0; r < 2; ++r) {
        const int ich = r * 32 + g * 8;
        uint4 dw;
        dw.x = pk2(lp[ich + 0], lp[ich + 1]);
        dw.y = pk2(lp[ich + 2], lp[ich + 3]);
        dw.z = pk2(lp[ich + 4], lp[ich + 5]);
        dw.w = pk2(lp[ich + 6], lp[ich + 7]);
        *reinterpret_cast<uint4*>(dst + r * 64 + g * 16) = dw;
    }
}

// ============ kernel 3: og-split conv with ry-fastest intra-XCD order (R15 verbatim) ============
__global__ __launch_bounds__(256, 3) void conv_mfma_ogsplit(
    const char* __restrict__ ws, float* __restrict__ out)
{
    __shared__ __align__(16) char lx[6 * 8448];   // 50688 B (x3 = 152064 <= 163840)

    const int tid  = threadIdx.x;
    const int lane = tid & 63;
    const int wv   = tid >> 6;
    const int n_l  = lane & 15;
    const int G_l  = lane >> 4;

    // XCD-aware swizzle, ry-FASTEST within XCD (validated R15: DRAM write-stream locality)
    const int bid = blockIdx.x;
    const int wg  = (bid & 7) * 512 + (bid >> 3);
    const int b   = wg >> 8;
    const int cbk = (wg >> 6) & 3;    // column band: slowest within batch
    const int ry  = wg & 63;          // row tile: FASTEST
    const int gc0 = cbk * 64;
    const int gr0 = ry * 4;

    const char* xTb = ws + AFRAG_BYTES + (size_t)b * XT_IMGB;
    const unsigned abase = (unsigned)((wv << 10) + (n_l << 6) + (G_l << 4));

    // ---- async stage (validated R8-R15): 54 wave-wide 16B/lane loads, pre-swizzled source
    // so LDS slot s holds global (px = s>>3, sub = (s&7) ^ ((s>>3)&7)) ----
    const unsigned laneoff = ((unsigned)(lane >> 3) << 7)
                           + ((unsigned)((lane & 7) ^ (lane >> 3)) << 4);
    #pragma unroll
    for (int t = 0; t < 14; ++t) {
        const int i = wv + 4 * t;
        if (i >= 54) break;                       // wave-uniform
        const int row = i / 9;
        const int k   = i - row * 9;
        const char* src = xTb + (size_t)(gr0 + row) * XT_ROWB
                        + ((unsigned)gc0 << 7) + ((unsigned)k << 10) + laneoff;
        if (k < 8 || lane < 16)                   // k==8: 256B tail (16 lanes)
            __builtin_amdgcn_global_load_lds(
                (const AS1 void*)src,
                (AS3 void*)&lx[row * 8448 + (k << 10)], 16, 0, 0);
    }

    // ---- A-frags: h=0 half resident (9 frags = 36 VGPR); h=1 trio-reloaded mid-loop ----
    short8 A[9];
#define LOADA(idx, kc) A[idx] = *reinterpret_cast<const short8*>(ws + ((kc) << 12) + abase)
    #pragma unroll
    for (int kc = 0; kc < 9; ++kc) LOADA(kc, kc);

    floatx4 acc[4][4];   // [cb][fr]
    #pragma unroll
    for (int cb = 0; cb < 4; ++cb)
        #pragma unroll
        for (int fr = 0; fr < 4; ++fr) acc[cb][fr] = (floatx4){0.f, 0.f, 0.f, 0.f};

    __syncthreads();   // drains stage + A loads (vmcnt 0) + barrier

    // ---- main loop: 6 phases (kw,h) x 4 cb units; per unit 6 ds_read_b128 + 12 MFMA ----
    #pragma unroll
    for (int ph = 0; ph < 6; ++ph) {
        const int kw = ph % 3, h = ph / 3;
        if (ph >= 1 && ph <= 3) {
            const int r = ph - 1;
            LOADA(r,     9 + r);
            LOADA(r + 3, 12 + r);
            LOADA(r + 6, 15 + r);
        }
        #pragma unroll
        for (int cb = 0; cb < 4; ++cb) {
            const int px = cb * 16 + n_l + kw;
            const int bo = (px << 7) + ((((h << 2) | G_l) ^ (px & 7)) << 4);
            uint4 B[6];
            #pragma unroll
            for (int j = 0; j < 6; ++j)
                B[j] = *reinterpret_cast<const uint4*>(&lx[j * 8448 + bo]);
            #pragma unroll
            for (int kh = 0; kh < 3; ++kh) {
                const short8 a = A[kh * 3 + kw];
                #pragma unroll
                for (int fr = 0; fr < 4; ++fr)
                    acc[cb][fr] = __builtin_amdgcn_mfma_f32_16x16x32_bf16(
                        a, __builtin_bit_cast(short8, B[fr + kh]), acc[cb][fr], 0, 0, 0);
            }
        }
    }
#undef LOADA

    // ---- epilogue: R12/R14/R15's VALIDATED block-cooperative in-LDS transpose ----
    float* lf = (float*)lx;
    #pragma unroll
    for (int half = 0; half < 2; ++half) {
        __syncthreads();   // previous readers done
        if ((wv >> 1) == half) {
            const int ocl16 = (wv & 1) << 4;   // 0 / 16 within the 32-oc half
            #pragma unroll
            for (int cb = 0; cb < 4; ++cb)
                #pragma unroll
                for (int fr = 0; fr < 4; ++fr)
                    #pragma unroll
                    for (int ri = 0; ri < 4; ++ri)
                        lf[((ocl16 + (G_l << 2) + ri) * 4 + fr) * 68 + cb * 16 + n_l]
                            = acc[cb][fr][ri];
        }
        __syncthreads();
        const int q = tid & 15;
        #pragma unroll
        for (int j = 0; j < 8; ++j) {
            const int row = (tid >> 4) + (j << 4);       // 0..127
            const int ocl = row >> 2, fr = row & 3;
            const float4 v = *reinterpret_cast<const float4*>(&lf[row * 68 + (q << 2)]);
            float* op = out + ((size_t)b * OCH + half * 32 + ocl) * HW
                            + (size_t)(gr0 + fr) * WW + gc0 + (q << 2);
            *reinterpret_cast<float4*>(op) = v;          // 256B contiguous runs
        }
    }
}

// ============ fallback: R4 validated LDS-staging conv (if ws too small) ============
#define TR 4
#define TC 64
#define XROWS 6
#define XCOLS 66
#define XPIXB 64
#define XROWB (XCOLS * XPIXB)
#define XHALFB (XROWS * XROWB)
#define LDS_BYTES (2 * XHALFB)

__global__ __launch_bounds__(256, 2) void conv_mfma_fallback(
    const float* __restrict__ x,
    const unsigned int* __restrict__ wfrag,
    float* __restrict__ out)
{
    __shared__ __align__(16) char lds[LDS_BYTES];
    const int tid  = threadIdx.x;
    const int lane = tid & 63;
    const int wv   = tid >> 6;
    const int n_l  = lane & 15;
    const int G_l  = lane >> 4;

    short8 afrag[18];
    {
        const int oc_l = (wv << 4) + n_l;
        const char* wsb = (const char*)wfrag;
        #pragma unroll
        for (int kc = 0; kc < 18; ++kc)
            afrag[kc] = *reinterpret_cast<const short8*>(
                wsb + (((kc * 64 + oc_l) * 4 + G_l) << 4));
    }

    const int gr0 = blockIdx.y * TR;
    const int gc0 = blockIdx.x * TC;
    const int b   = blockIdx.z;
    const float* xb = x + (size_t)b * ICH * HW;

    for (int p = wv; p < 48; p += 4) {
        const int h  = p / 24;
        const int pr = (p % 24) >> 2;
        const int G  = p & 3;
        const int gr = gr0 - 1 + pr;
        const int icb = h * 32 + G * 8;
        const bool rok = ((unsigned)gr < (unsigned)HH);
        {
            const float* src = xb + (size_t)icb * HW + (size_t)gr * WW + gc0 + lane;
            float v[8];
            #pragma unroll
            for (int qq = 0; qq < 8; ++qq) v[qq] = rok ? src[(size_t)qq * HW] : 0.f;
            const int pc = lane + 1;
            const int addr = h*XHALFB + pr*XROWB + pc*XPIXB + ((G ^ ((pc >> 1) & 3)) << 4);
            uint4 w4; w4.x = pk2(v[0], v[1]); w4.y = pk2(v[2], v[3]);
            w4.z = pk2(v[4], v[5]); w4.w = pk2(v[6], v[7]);
            *reinterpret_cast<uint4*>(&lds[addr]) = w4;
        }
        if (lane < 2) {
            const int pc = lane * 65;
            const int gc = gc0 - 1 + pc;
            const bool ok = rok && ((unsigned)gc < (unsigned)WW);
            const float* src = xb + (size_t)icb * HW + (size_t)gr * WW + gc;
            float v[8];
            #pragma unroll
            for (int qq = 0; qq < 8; ++qq) v[qq] = ok ? src[(size_t)qq * HW] : 0.f;
            const int addr = h*XHALFB + pr*XROWB + pc*XPIXB + ((G ^ ((pc >> 1) & 3)) << 4);
            uint4 w4; w4.x = pk2(v[0], v[1]); w4.y = pk2(v[2], v[3]);
            w4.z = pk2(v[4], v[5]); w4.w = pk2(v[6], v[7]);
            *reinterpret_cast<uint4*>(&lds[addr]) = w4;
        }
    }
    __syncthreads();

    int colp[4][3];
    #pragma unroll
    for (int cbq = 0; cbq < 4; ++cbq)
        #pragma unroll
        for (int kw = 0; kw < 3; ++kw) {
            const int pcv = cbq * 16 + n_l + kw;
            colp[cbq][kw] = pcv * XPIXB + ((G_l ^ ((pcv >> 1) & 3)) << 4);
        }

    floatx4 acc[16];
    #pragma unroll
    for (int f = 0; f < 16; ++f) acc[f] = (floatx4){0.f, 0.f, 0.f, 0.f};

    #pragma unroll
    for (int kc = 0; kc < 18; ++kc) {
        const int h = kc / 9, tap = kc % 9;
        const int kh = tap / 3, kw = tap % 3;
        #pragma unroll
        for (int f = 0; f < 16; ++f) {
            const int fr = f >> 2, cbq = f & 3;
            const short8 bfrag = *reinterpret_cast<const short8*>(
                &lds[h*XHALFB + (fr + kh)*XROWB + colp[cbq][kw]]);
            acc[f] = __builtin_amdgcn_mfma_f32_16x16x32_bf16(afrag[kc], bfrag, acc[f], 0, 0, 0);
        }
    }

    float* ob = out + ((size_t)(b*OCH + (wv << 4) + (G_l << 2)) * HW)
                    + (size_t)gr0 * WW + gc0 + n_l;
    #pragma unroll
    for (int f = 0; f < 16; ++f) {
        const int fr = f >> 2, cbq = f & 3;
        #pragma unroll
        for (int ri = 0; ri < 4; ++ri)
            ob[(size_t)ri * HW + fr * WW + cbq * 16] = acc[f][ri];
    }
}

extern "C" void kernel_launch(void* const* d_in, const int* in_sizes, int n_in,
                              void* d_out, int out_size, void* d_ws, size_t ws_size,
                              hipStream_t stream) {
    const float* x = (const float*)d_in[0];
    const float* w = (const float*)d_in[1];
    float* out = (float*)d_out;
    unsigned int* wsf = (unsigned int*)d_ws;

    weight_prep_kernel<<<dim3(4), 64, 0, stream>>>(w, wsf);

    if (ws_size >= WS_NEEDED) {
        char* xT = (char*)d_ws + AFRAG_BYTES;
        transpose_pad_kernel<<<dim3(4, XT_PIX, BATCH), 256, 0, stream>>>(x, xT);
        conv_mfma_ogsplit<<<dim3(4096), 256, 0, stream>>>((const char*)d_ws, out);
    } else {
        conv_mfma_fallback<<<dim3(4, 64, BATCH), 256, 0, stream>>>(x, wsf, out);
    }
}